// Round 11
// baseline (323.681 us; speedup 1.0000x reference)
//
#include <hip/hip_runtime.h>
#include <hip/hip_bf16.h>

// Causal MHA forward — full bf16 pipeline, fp32 softmax/accumulate.
//   x      [4, 2048, 1024]   d_in[0] fp32
//   w_qkv  [3, 16, 64, 1024] d_in[1] fp32 ([3072,1024], K contiguous)
//   w_o    [1024, 1024]      d_in[2] fp32 (y = attn_cat @ w_o^T)
//   out    [4, 2048, 1024]   d_out   fp32
// ws (bf16): xb | wqb | wob | qkv | attn_cat = 92 MB.
// Softmax in exp2-domain: Q pre-scaled by 0.125*log2(e) in the QKV GEMM.

#define D_MODEL 1024
#define NUM_HEADS 16
#define D_KD 64
#define B_SZ 4
#define S_LEN 2048
#define ROWS (B_SZ * S_LEN)   // 8192
#define QKV_N (3 * D_MODEL)   // 3072

#define QSCALE 0.18033688f    // 0.125 * log2(e)
#define DEFER_THR 11.5415603f // 8 * log2(e)

typedef __attribute__((ext_vector_type(8))) short short8;
typedef __attribute__((ext_vector_type(4))) float f32x4;
typedef __attribute__((ext_vector_type(16))) float f32x16;
typedef unsigned short ushort_t;

__device__ __forceinline__ ushort_t bf1(float a) {
    return __builtin_bit_cast(unsigned short, __float2bfloat16(a));
}
__device__ __forceinline__ unsigned packbf2(float a, float b) {
    return (unsigned)bf1(a) | ((unsigned)bf1(b) << 16);
}
// async global->LDS, 16B per lane. LDS dest = wave-uniform base + lane*16.
__device__ __forceinline__ void gload16(void* lds, const void* g) {
    __builtin_amdgcn_global_load_lds(
        (const __attribute__((address_space(1))) unsigned int*)(g),
        (__attribute__((address_space(3))) unsigned int*)(lds), 16, 0, 0);
}

// ---------------------------------------------------------------------------
// fp32 -> bf16 conversion (grid-stride, float4 in / uint2 out)
// ---------------------------------------------------------------------------
__global__ __launch_bounds__(256) void cvt_bf16(const float* __restrict__ src,
                                                ushort_t* __restrict__ dst, int n4) {
    int i = blockIdx.x * blockDim.x + threadIdx.x;
    const int stride = gridDim.x * blockDim.x;
    for (; i < n4; i += stride) {
        float4 v = reinterpret_cast<const float4*>(src)[i];
        uint2 u;
        u.x = packbf2(v.x, v.y);
        u.y = packbf2(v.z, v.w);
        *reinterpret_cast<uint2*>(&dst[(size_t)i * 4]) = u;
    }
}

// ---------------------------------------------------------------------------
// MFMA GEMM: C = A * B^T. A:[M,K] bf16, B:[N,K] bf16.
// 128x128 tile, BK=64 (two 32-k sub-blocks, each identical to the verified
// BK=32 pattern), 4 waves 2x2, global_load_lds x8/thread/step.
// Bijective XCD swizzle (T1, m204) on the linearized grid.
// MODE 0: scatter bf16 into qkv[q][b][h][s][k], xQSCALE on the Q third.
// MODE 1: fp32 row-major C.
// ---------------------------------------------------------------------------
template <int MODE>
__global__ __launch_bounds__(256) void gemm_bt_bf16(const ushort_t* __restrict__ A,
                                                    const ushort_t* __restrict__ Bm,
                                                    ushort_t* __restrict__ Cb,
                                                    float* __restrict__ Cf,
                                                    int M, int N, int K) {
    __shared__ ushort_t As[2 * 4096];   // [kh][128 rows][32 k] linear, 64B rows
    __shared__ ushort_t Bs[2 * 4096];

    // ---- T1 XCD swizzle (nwg % 8 == 0 for all our grids)
    const int nwg = gridDim.x * gridDim.y;
    const int orig = blockIdx.y * gridDim.x + blockIdx.x;
    const int cpx = nwg >> 3;
    const int swz = (orig & 7) * cpx + (orig >> 3);
    const int bx = swz % gridDim.x;
    const int by = swz / gridDim.x;

    const int t = threadIdx.x;
    const int lane = t & 63;
    const int w = t >> 6;
    const int wr = w >> 1, wc = w & 1;
    const int row0 = by * 128;
    const int col0 = bx * 128;

    const int srow = t >> 2;          // 0..63 (+64 for i2=1)
    const int sk8 = (t & 3) << 3;     // 0,8,16,24

    const ushort_t* Ag = A + (size_t)(row0 + srow) * K + sk8;
    const ushort_t* Bg = Bm + (size_t)(col0 + srow) * K + sk8;

    f32x4 acc[4][4];
#pragma unroll
    for (int m = 0; m < 4; ++m)
#pragma unroll
        for (int n = 0; n < 4; ++n)
#pragma unroll
            for (int j = 0; j < 4; ++j) acc[m][n][j] = 0.f;

    const int q8 = (lane >> 4) << 3;
    const int frA = wr * 64 + (lane & 15);
    const int frB = wc * 64 + (lane & 15);
    const int NT = K >> 6;   // BK=64 steps

    for (int kt = 0; kt < NT; ++kt) {
        const int k0 = kt << 6;
        __syncthreads();                       // prev frag reads done
#pragma unroll
        for (int kh = 0; kh < 2; ++kh) {
            const int kw = k0 + kh * 32;
#pragma unroll
            for (int i2 = 0; i2 < 2; ++i2) {
                ushort_t* dA = &As[kh * 4096 + (i2 * 256 + t) * 8];
                ushort_t* dB = &Bs[kh * 4096 + (i2 * 256 + t) * 8];
                gload16(dA, Ag + (size_t)i2 * 64 * K + kw);
                gload16(dB, Bg + (size_t)i2 * 64 * K + kw);
            }
        }
        __syncthreads();                       // drains vmcnt(0)

        short8 afr[4][2], bfr[4][2];
#pragma unroll
        for (int m = 0; m < 4; ++m)
#pragma unroll
            for (int kh = 0; kh < 2; ++kh)
                afr[m][kh] = *reinterpret_cast<const short8*>(
                    &As[kh * 4096 + (frA + m * 16) * 32 + q8]);
#pragma unroll
        for (int n = 0; n < 4; ++n)
#pragma unroll
            for (int kh = 0; kh < 2; ++kh)
                bfr[n][kh] = *reinterpret_cast<const short8*>(
                    &Bs[kh * 4096 + (frB + n * 16) * 32 + q8]);
#pragma unroll
        for (int kh = 0; kh < 2; ++kh)
#pragma unroll
            for (int m = 0; m < 4; ++m)
#pragma unroll
                for (int n = 0; n < 4; ++n)
                    acc[m][n] = __builtin_amdgcn_mfma_f32_16x16x32_bf16(
                        afr[m][kh], bfr[n][kh], acc[m][n], 0, 0, 0);
    }

    // C/D frag: col = lane&15, row = (lane>>4)*4 + reg.
    const int orow = row0 + wr * 64 + ((lane >> 4) << 2);
    const int ocol = col0 + wc * 64 + (lane & 15);
#pragma unroll
    for (int m = 0; m < 4; ++m)
#pragma unroll
        for (int n = 0; n < 4; ++n) {
            const int cg = ocol + n * 16;
#pragma unroll
            for (int j = 0; j < 4; ++j) {
                const int rg = orow + m * 16 + j;
                float v = acc[m][n][j];
                if (MODE == 0) {
                    const int q = cg >> 10, hh = (cg >> 6) & 15, kk = cg & 63;
                    const int bb = rg >> 11, s = rg & 2047;
                    if (q == 0) v *= QSCALE;   // fold 1/sqrt(d_k)*log2e into Q
                    Cb[((((size_t)q * B_SZ + bb) * NUM_HEADS + hh) * S_LEN + s) * D_KD + kk] =
                        bf1(v);
                } else {
                    Cf[(size_t)rg * N + cg] = v;
                }
            }
        }
}

// ---------------------------------------------------------------------------
// Flash attention v5 — v3's verified synchronous staging (125.4 us, zero
// bank conflicts) + exp2-domain softmax, compiler cvt_pk packing, setprio.
// ---------------------------------------------------------------------------
__global__ __launch_bounds__(512, 2) void flash_attn_mfma_v5(const ushort_t* __restrict__ qkv,
                                                             ushort_t* __restrict__ attn_out) {
    const int qb = (int)gridDim.x - 1 - (int)blockIdx.x;   // heavy blocks first
    const int h = blockIdx.y;
    const int b = blockIdx.z;
    const int t = threadIdx.x;
    const int lane = t & 63;
    const int w = t >> 6;
    const int l31 = lane & 31;
    const int hi = lane >> 5;

    __shared__ ushort_t smem[256 * 72];
    __shared__ float fbuf[8][32];
    ushort_t* Qs = smem;
    ushort_t* Ks = smem;              // aliased; Q frags hoisted first
    ushort_t* Vt = smem + 64 * 72;

    const size_t head_elems = (size_t)S_LEN * D_KD;
    const ushort_t* Qg = qkv + (((size_t)0 * B_SZ + b) * NUM_HEADS + h) * head_elems;
    const ushort_t* Kg = qkv + (((size_t)1 * B_SZ + b) * NUM_HEADS + h) * head_elems;
    const ushort_t* Vg = qkv + (((size_t)2 * B_SZ + b) * NUM_HEADS + h) * head_elems;

    const int q0 = qb * 256;
    const int qmin = q0 + 32 * w;
    const int nt = 4 * (qb + 1);

    // ---- stage Q tile [256][64] bf16 (pre-scaled by QSCALE in GEMM)
#pragma unroll
    for (int lx = 0; lx < 4; ++lx) {
        int idx = t + lx * 512;
        int r = idx >> 3;
        int c8 = (idx & 7) << 3;
        *reinterpret_cast<uint4*>(&Qs[r * 72 + c8]) =
            *reinterpret_cast<const uint4*>(&Qg[(size_t)(q0 + r) * D_KD + c8]);
    }
    __syncthreads();

    short8 qfr[4];
#pragma unroll
    for (int ks = 0; ks < 4; ++ks)
        qfr[ks] = *reinterpret_cast<const short8*>(&Qs[(32 * w + l31) * 72 + 16 * ks + 8 * hi]);

    f32x16 oacc[2];
#pragma unroll
    for (int n = 0; n < 2; ++n)
#pragma unroll
        for (int j = 0; j < 16; ++j) oacc[n][j] = 0.f;
    float m = -1e30f, lsum = 0.f;

    for (int tt = 0; tt < nt; ++tt) {
        const int c0 = tt * 64;
        __syncthreads();   // smem consumers done (Q frags hoisted on iter 0)

        if (w < 4) {
            // warps 0..3: copy K tile [64][64] bf16
#pragma unroll
            for (int i = 0; i < 2; ++i) {
                int j = t + i * 256;
                int r = j >> 3;
                int c8 = (j & 7) << 3;
                *reinterpret_cast<uint4*>(&Ks[r * 72 + c8]) =
                    *reinterpret_cast<const uint4*>(&Kg[(size_t)(c0 + r) * D_KD + c8]);
            }
        } else {
            // warps 4..7: V transposed -> Vt[d][t]; conflict-free b32 writes
            int t2 = t - 256;
            int tp = t2 & 31, dg = t2 >> 5;
            int t0 = tp * 2, d0 = dg * 8;
            uint4 va = *reinterpret_cast<const uint4*>(&Vg[(size_t)(c0 + t0) * D_KD + d0]);
            uint4 vb = *reinterpret_cast<const uint4*>(&Vg[(size_t)(c0 + t0 + 1) * D_KD + d0]);
            const ushort_t* ua = reinterpret_cast<const ushort_t*>(&va);
            const ushort_t* ub = reinterpret_cast<const ushort_t*>(&vb);
#pragma unroll
            for (int d = 0; d < 8; ++d) {
                unsigned u = (unsigned)ua[d] | ((unsigned)ub[d] << 16);
                *reinterpret_cast<unsigned*>(&Vt[(d0 + d) * 72 + t0]) = u;
            }
        }
        __syncthreads();

        for (int st = 0; st < 2; ++st) {
            const int t0s = c0 + 32 * st;
            if (t0s > qmin) break;          // wave-uniform; no barriers below
            const bool diag = (t0s == qmin);

            // ---- S^T = mfma(K, Q): lane holds S[q=l31][t=tloc(reg,hi)]
            f32x16 s;
#pragma unroll
            for (int j = 0; j < 16; ++j) s[j] = 0.f;
            __builtin_amdgcn_s_setprio(1);
#pragma unroll
            for (int ks = 0; ks < 4; ++ks) {
                short8 ka = *reinterpret_cast<const short8*>(
                    &Ks[(32 * st + l31) * 72 + 16 * ks + 8 * hi]);
                s = __builtin_amdgcn_mfma_f32_32x32x16_bf16(ka, qfr[ks], s, 0, 0, 0);
            }
            __builtin_amdgcn_s_setprio(0);
            if (diag) {
#pragma unroll
                for (int reg = 0; reg < 16; ++reg) {
                    const int tloc = (reg & 3) + 8 * (reg >> 2) + 4 * hi;
                    if (tloc > l31) s[reg] = -1e30f;
                }
            }

            // ---- in-register online softmax, exp2 domain (q = l31)
            float pm = s[0];
#pragma unroll
            for (int reg = 1; reg < 16; ++reg) pm = fmaxf(pm, s[reg]);
            pm = fmaxf(pm, __shfl_xor(pm, 32));

            if (!__all(pm <= m + DEFER_THR)) {   // defer-max (T13)
                const float mnew = fmaxf(m, pm);
                const float al = exp2f(m - mnew);
                m = mnew;
                lsum *= al;
                fbuf[w][l31] = al;
#pragma unroll
                for (int g = 0; g < 4; ++g) {
                    float4 a4 = *reinterpret_cast<float4*>(&fbuf[w][8 * g + 4 * hi]);
                    const float* ap = reinterpret_cast<const float*>(&a4);
#pragma unroll
                    for (int j = 0; j < 4; ++j) {
                        oacc[0][4 * g + j] *= ap[j];
                        oacc[1][4 * g + j] *= ap[j];
                    }
                }
            }

            float p[16];
            float ps = 0.f;
#pragma unroll
            for (int reg = 0; reg < 16; ++reg) {
                p[reg] = exp2f(s[reg] - m);
                ps += p[reg];
            }
            ps += __shfl_xor(ps, 32);
            lsum += ps;

            // ---- pack P bf16 (compiler cvt_pk), exchange halves, A-frags
            unsigned pk[8], sw[8];
#pragma unroll
            for (int i = 0; i < 8; ++i) pk[i] = packbf2(p[2 * i], p[2 * i + 1]);
#pragma unroll
            for (int i = 0; i < 8; ++i) sw[i] = (unsigned)__shfl_xor((int)pk[i], 32);

            union { unsigned u[4]; short8 s8; } a0, a1;
            a0.u[0] = hi ? sw[2] : pk[0];
            a0.u[1] = hi ? sw[3] : pk[1];
            a0.u[2] = hi ? pk[2] : sw[0];
            a0.u[3] = hi ? pk[3] : sw[1];
            a1.u[0] = hi ? sw[6] : pk[4];
            a1.u[1] = hi ? sw[7] : pk[5];
            a1.u[2] = hi ? pk[6] : sw[4];
            a1.u[3] = hi ? pk[7] : sw[5];

            // ---- PV: O[q][d] += P[q][t] V[t][d]
            __builtin_amdgcn_s_setprio(1);
#pragma unroll
            for (int n = 0; n < 2; ++n) {
                const ushort_t* vrow = &Vt[(32 * n + l31) * 72 + 32 * st + 8 * hi];
                short8 vb0 = *reinterpret_cast<const short8*>(vrow);
                short8 vb1 = *reinterpret_cast<const short8*>(vrow + 16);
                oacc[n] = __builtin_amdgcn_mfma_f32_32x32x16_bf16(a0.s8, vb0, oacc[n], 0, 0, 0);
                oacc[n] = __builtin_amdgcn_mfma_f32_32x32x16_bf16(a1.s8, vb1, oacc[n], 0, 0, 0);
            }
            __builtin_amdgcn_s_setprio(0);
        }
    }

    // ---- epilogue: normalize and store bf16 attn_cat [b, s, h*64 + d]
    const float inv = 1.f / lsum;
    fbuf[w][l31] = inv;
#pragma unroll
    for (int g = 0; g < 4; ++g) {
        float4 i4 = *reinterpret_cast<float4*>(&fbuf[w][8 * g + 4 * hi]);
        const float* ip = reinterpret_cast<const float*>(&i4);
#pragma unroll
        for (int j = 0; j < 4; ++j) {
            const int reg = 4 * g + j;
            const int qrow = q0 + 32 * w + 8 * g + 4 * hi + j;
            const size_t base = ((size_t)(b * S_LEN + qrow)) * D_MODEL + h * D_KD + l31;
            attn_out[base] = bf1(oacc[0][reg] * ip[j]);
            attn_out[base + 32] = bf1(oacc[1][reg] * ip[j]);
        }
    }
}

// ---------------------------------------------------------------------------
extern "C" void kernel_launch(void* const* d_in, const int* in_sizes, int n_in,
                              void* d_out, int out_size, void* d_ws, size_t ws_size,
                              hipStream_t stream) {
    const float* x = (const float*)d_in[0];
    const float* w_qkv = (const float*)d_in[1];
    const float* w_o = (const float*)d_in[2];
    float* out = (float*)d_out;

    ushort_t* xb = (ushort_t*)d_ws;                 //  8,388,608
    ushort_t* wqb = xb + 8388608;                   //  3,145,728
    ushort_t* wob = wqb + 3145728;                  //  1,048,576
    ushort_t* qkvb = wob + 1048576;                 // 25,165,824
    ushort_t* attnb = qkvb + 25165824;              //  8,388,608

    cvt_bf16<<<2048, 256, 0, stream>>>(x, xb, 8388608 / 4);
    cvt_bf16<<<1024, 256, 0, stream>>>(w_qkv, wqb, 3145728 / 4);
    cvt_bf16<<<512, 256, 0, stream>>>(w_o, wob, 1048576 / 4);

    gemm_bt_bf16<0><<<dim3(QKV_N / 128, ROWS / 128), dim3(256), 0, stream>>>(
        xb, wqb, qkvb, nullptr, ROWS, QKV_N, D_MODEL);
    flash_attn_mfma_v5<<<dim3(S_LEN / 256, NUM_HEADS, B_SZ), dim3(512), 0, stream>>>(qkvb, attnb);
    gemm_bt_bf16<1><<<dim3(D_MODEL / 128, ROWS / 128), dim3(256), 0, stream>>>(
        attnb, wob, nullptr, out, ROWS, D_MODEL, D_MODEL);
}